// Round 1
// baseline (3518.036 us; speedup 1.0000x reference)
//
#include <hip/hip_runtime.h>
#include <hip/hip_bf16.h>

// HMM forward, linear-space with per-step rescaling.
// S=1024 states, V=512 obs, B=64 batch, T=128 steps.
//
// ws layout (bytes):
//   P_frag : 0x000000  [64 wg][32 kk][64 lane][8 elem] bf16   (2 MB)  B-fragments of P=softmax(trans)
//   emisP  : 0x200000  [1024][512] bf16                       (1 MB)  softmax(emission) probabilities
//   prior_p: 0x300000  [1024] f32                             (4 KB)
//   rstat  : 0x301000  [1024][2] f32 (rowmax, 1/rowsum)       (8 KB)
//   albuf  : 0x310000  [2][64][1024] bf16 ping-pong alpha     (256 KB)
//   pmax   : 0x350000  [2][64 wg][64 b] f32                   (32 KB)
//   flags  : 0x358000  [64] u32

typedef __attribute__((ext_vector_type(8))) short short8;
typedef __attribute__((ext_vector_type(4))) float f32x4;

__device__ __forceinline__ float bf2f(short x) {
  unsigned u = ((unsigned)(unsigned short)x) << 16;
  return __builtin_bit_cast(float, u);
}
__device__ __forceinline__ short f2bf(float f) {
  unsigned u = __builtin_bit_cast(unsigned, f);
  u += 0x7fffu + ((u >> 16) & 1u);
  return (short)(u >> 16);
}
__device__ __forceinline__ float waveReduceMax(float v) {
  #pragma unroll
  for (int d = 1; d < 64; d <<= 1) v = fmaxf(v, __shfl_xor(v, d, 64));
  return v;
}
__device__ __forceinline__ float waveReduceSum(float v) {
  #pragma unroll
  for (int d = 1; d < 64; d <<= 1) v += __shfl_xor(v, d, 64);
  return v;
}

// per-row max and 1/sumexp for trans rows (1024 cols)
__global__ __launch_bounds__(256) void k_rowstat(const float* __restrict__ x,
                                                 float* __restrict__ rstat) {
  __shared__ float sm[8];
  const int row = blockIdx.x;
  const float* p = x + row * 1024;
  const int tid = threadIdx.x;
  float m = -1e30f;
  for (int i = tid; i < 1024; i += 256) m = fmaxf(m, p[i]);
  m = waveReduceMax(m);
  if ((tid & 63) == 0) sm[tid >> 6] = m;
  __syncthreads();
  m = fmaxf(fmaxf(sm[0], sm[1]), fmaxf(sm[2], sm[3]));
  float s = 0.f;
  for (int i = tid; i < 1024; i += 256) s += __expf(p[i] - m);
  s = waveReduceSum(s);
  if ((tid & 63) == 0) sm[4 + (tid >> 6)] = s;
  __syncthreads();
  if (tid == 0) {
    float tot = sm[4] + sm[5] + sm[6] + sm[7];
    rstat[row * 2] = m;
    rstat[row * 2 + 1] = 1.0f / tot;
  }
}

// scatter P = softmax(trans) rows into MFMA B-fragment order, bf16.
// B-frag layout assumed for v_mfma_f32_16x16x32_bf16:
//   lane l holds cols n = l&15, k = (l>>4)*8 + e, e = 0..7 (k-consecutive 8)
__global__ __launch_bounds__(256) void k_fillP(const float* __restrict__ trans,
                                               const float* __restrict__ rstat,
                                               short* __restrict__ P_frag) {
  __shared__ float st[512];  // [32 i_local][16 j_local]
  const int w = blockIdx.x, tid = threadIdx.x;
  for (int kk = 0; kk < 32; ++kk) {
    for (int idx = tid; idx < 512; idx += 256) {
      int il = idx >> 4, jl = idx & 15;
      int i = kk * 32 + il, j = w * 16 + jl;
      float m = rstat[i * 2], invs = rstat[i * 2 + 1];
      st[idx] = __expf(trans[i * 1024 + j] - m) * invs;
    }
    __syncthreads();
    for (int idx = tid; idx < 512; idx += 256) {
      int lane = idx >> 3, e = idx & 7;
      int il = ((lane >> 4) & 3) * 8 + e, jl = lane & 15;
      P_frag[w * 16384 + kk * 512 + idx] = f2bf(st[il * 16 + jl]);
    }
    __syncthreads();
  }
}

// emission probabilities: row softmax over 512, store bf16 row-major
__global__ __launch_bounds__(256) void k_emis(const float* __restrict__ x,
                                              short* __restrict__ o) {
  __shared__ float sm[8];
  const int row = blockIdx.x;
  const float* p = x + row * 512;
  const int tid = threadIdx.x;
  float m = -1e30f;
  for (int i = tid; i < 512; i += 256) m = fmaxf(m, p[i]);
  m = waveReduceMax(m);
  if ((tid & 63) == 0) sm[tid >> 6] = m;
  __syncthreads();
  m = fmaxf(fmaxf(sm[0], sm[1]), fmaxf(sm[2], sm[3]));
  float s = 0.f;
  for (int i = tid; i < 512; i += 256) s += __expf(p[i] - m);
  s = waveReduceSum(s);
  if ((tid & 63) == 0) sm[4 + (tid >> 6)] = s;
  __syncthreads();
  float invs = 1.0f / (sm[4] + sm[5] + sm[6] + sm[7]);
  for (int i = tid; i < 512; i += 256) o[row * 512 + i] = f2bf(__expf(p[i] - m) * invs);
}

// prior probabilities f32
__global__ __launch_bounds__(256) void k_prior(const float* __restrict__ x,
                                               float* __restrict__ o) {
  __shared__ float sm[8];
  const int tid = threadIdx.x;
  float m = -1e30f;
  for (int i = tid; i < 1024; i += 256) m = fmaxf(m, x[i]);
  m = waveReduceMax(m);
  if ((tid & 63) == 0) sm[tid >> 6] = m;
  __syncthreads();
  m = fmaxf(fmaxf(sm[0], sm[1]), fmaxf(sm[2], sm[3]));
  float s = 0.f;
  for (int i = tid; i < 1024; i += 256) s += __expf(x[i] - m);
  s = waveReduceSum(s);
  if ((tid & 63) == 0) sm[4 + (tid >> 6)] = s;
  __syncthreads();
  float invs = 1.0f / (sm[4] + sm[5] + sm[6] + sm[7]);
  for (int i = tid; i < 1024; i += 256) o[i] = __expf(x[i] - m) * invs;
}

// persistent main kernel: 64 wgs x 256 threads; wg w owns j-tile [16w,16w+16)
__global__ __launch_bounds__(256, 1) void hmm_main(
    const int* __restrict__ value, const float* __restrict__ prior_p,
    const short* __restrict__ P_frag, const short* __restrict__ emisP,
    short* __restrict__ albuf, float* __restrict__ pmax,
    unsigned int* __restrict__ flags, float* __restrict__ out) {
  __shared__ __align__(16) short p_lds[16384];   // [32 kk][64 lane][8] B-fragments
  __shared__ __align__(16) short e_lds[16 * 513];// emis rows, padded
  __shared__ float s_lds[64];
  __shared__ float lsc_lds[64];
  __shared__ float red_lds[4];

  const int w = blockIdx.x;
  const int tid = threadIdx.x;
  const int lane = tid & 63;
  const int wid = tid >> 6;       // wave id = M-tile (16 batches each)
  const int jl = lane & 15;       // j within tile / C col
  const int kg = lane >> 4;       // k-group
  const int b0 = wid * 16 + kg * 4;  // C rows: b0..b0+3 (reg r)

  {
    const short8* src = (const short8*)(P_frag + w * 16384);
    short8* dst = (short8*)p_lds;
    #pragma unroll
    for (int i = 0; i < 8; ++i) dst[tid + i * 256] = src[tid + i * 256];
  }
  for (int i = tid; i < 16 * 512; i += 256) {
    int r = i >> 9, c = i & 511;
    e_lds[r * 513 + c] = emisP[(w * 16 + r) * 512 + c];
  }
  if (tid < 64) { s_lds[tid] = 1.f; lsc_lds[tid] = 0.f; }
  __syncthreads();

  // ---- t = 0: alpha0 = prior_p * E0 ----
  {
    float pj = prior_p[w * 16 + jl];
    float sv[4];
    #pragma unroll
    for (int r = 0; r < 4; ++r) {
      int obs = value[(b0 + r) * 128 + 0];
      sv[r] = pj * bf2f(e_lds[jl * 513 + obs]);
    }
    #pragma unroll
    for (int r = 0; r < 4; ++r)
      albuf[(b0 + r) * 1024 + w * 16 + jl] = f2bf(sv[r]);
    #pragma unroll
    for (int r = 0; r < 4; ++r) {
      float m0 = sv[r];
      m0 = fmaxf(m0, __shfl_xor(m0, 1, 64));
      m0 = fmaxf(m0, __shfl_xor(m0, 2, 64));
      m0 = fmaxf(m0, __shfl_xor(m0, 4, 64));
      m0 = fmaxf(m0, __shfl_xor(m0, 8, 64));
      sv[r] = m0;
    }
    if (jl == 0) {
      #pragma unroll
      for (int r = 0; r < 4; ++r) pmax[w * 64 + b0 + r] = sv[r];
    }
    __threadfence();
    __syncthreads();
    if (tid == 0)
      __hip_atomic_store(&flags[w], 1u, __ATOMIC_RELEASE, __HIP_MEMORY_SCOPE_AGENT);
  }

  // ---- main recurrence ----
  for (int t = 1; t < 128; ++t) {
    if (wid == 0) {
      int tries = 0;
      while (true) {
        unsigned f = __hip_atomic_load(&flags[lane], __ATOMIC_RELAXED, __HIP_MEMORY_SCOPE_AGENT);
        if (__all((int)(f >= (unsigned)t))) break;
        if (++tries > (1 << 20)) break;  // safety: no infinite hang
        __builtin_amdgcn_s_sleep(1);
      }
    }
    __syncthreads();
    __threadfence();  // acquire: make remote tiles + pmax visible

    if (wid == 0) {
      const float* pm = pmax + ((t - 1) & 1) * 4096;
      float m = -1e30f;
      #pragma unroll 8
      for (int i = 0; i < 64; ++i) m = fmaxf(m, pm[i * 64 + lane]);
      s_lds[lane] = 1.0f / m;          // identical across all wgs (same bits, same order)
      lsc_lds[lane] += logf(m);
    }
    __syncthreads();

    const short* aprev = albuf + ((t - 1) & 1) * 65536;
    const short8* abase = (const short8*)(aprev + (wid * 16 + jl) * 1024 + kg * 8);
    const short8* bb = (const short8*)p_lds + lane;
    f32x4 acc0 = {0.f, 0.f, 0.f, 0.f}, acc1 = {0.f, 0.f, 0.f, 0.f};
    #pragma unroll
    for (int kk = 0; kk < 32; kk += 2) {
      short8 a0 = abase[kk * 4];        // A: row = wid*16+jl, k = kk*32 + kg*8 ..+8
      short8 b0v = bb[kk * 64];         // B fragment from LDS
      acc0 = __builtin_amdgcn_mfma_f32_16x16x32_bf16(a0, b0v, acc0, 0, 0, 0);
      short8 a1 = abase[(kk + 1) * 4];
      short8 b1v = bb[(kk + 1) * 64];
      acc1 = __builtin_amdgcn_mfma_f32_16x16x32_bf16(a1, b1v, acc1, 0, 0, 0);
    }

    float sv[4];
    #pragma unroll
    for (int r = 0; r < 4; ++r) {
      int b = b0 + r;
      int obs = value[b * 128 + t];
      float E = bf2f(e_lds[jl * 513 + obs]);
      sv[r] = (acc0[r] + acc1[r]) * s_lds[b] * E;
    }
    short* acur = albuf + (t & 1) * 65536;
    #pragma unroll
    for (int r = 0; r < 4; ++r)
      acur[(b0 + r) * 1024 + w * 16 + jl] = f2bf(sv[r]);

    float* pmc = pmax + (t & 1) * 4096;
    #pragma unroll
    for (int r = 0; r < 4; ++r) {
      float m0 = sv[r];
      m0 = fmaxf(m0, __shfl_xor(m0, 1, 64));
      m0 = fmaxf(m0, __shfl_xor(m0, 2, 64));
      m0 = fmaxf(m0, __shfl_xor(m0, 4, 64));
      m0 = fmaxf(m0, __shfl_xor(m0, 8, 64));
      sv[r] = m0;
    }
    if (jl == 0) {
      #pragma unroll
      for (int r = 0; r < 4; ++r) pmc[w * 64 + b0 + r] = sv[r];
    }
    __threadfence();  // release: flush tile + pmax before flag
    __syncthreads();
    if (tid == 0)
      __hip_atomic_store(&flags[w], (unsigned)(t + 1), __ATOMIC_RELEASE, __HIP_MEMORY_SCOPE_AGENT);
  }

  // ---- final: out[b=w] = logscale[w] + log(sum_j alpha_127[w][j]) ----
  if (wid == 0) {
    int tries = 0;
    while (true) {
      unsigned f = __hip_atomic_load(&flags[lane], __ATOMIC_RELAXED, __HIP_MEMORY_SCOPE_AGENT);
      if (__all((int)(f >= 128u))) break;
      if (++tries > (1 << 20)) break;
      __builtin_amdgcn_s_sleep(1);
    }
  }
  __syncthreads();
  __threadfence();
  const short* arow = albuf + 65536 + w * 1024;  // t=127 -> half 1
  float part = 0.f;
  for (int i = tid; i < 1024; i += 256) part += bf2f(arow[i]);
  part = waveReduceSum(part);
  if (lane == 0) red_lds[wid] = part;
  __syncthreads();
  if (tid == 0) {
    float ssum = red_lds[0] + red_lds[1] + red_lds[2] + red_lds[3];
    out[w] = lsc_lds[w] + logf(ssum);
  }
}

extern "C" void kernel_launch(void* const* d_in, const int* in_sizes, int n_in,
                              void* d_out, int out_size, void* d_ws, size_t ws_size,
                              hipStream_t stream) {
  const int* value = (const int*)d_in[0];
  const float* prior = (const float*)d_in[1];
  const float* trans = (const float*)d_in[2];
  const float* emis = (const float*)d_in[3];
  char* ws = (char*)d_ws;
  short* P_frag = (short*)(ws + 0x000000);
  short* emisP = (short*)(ws + 0x200000);
  float* prior_p = (float*)(ws + 0x300000);
  float* rstat = (float*)(ws + 0x301000);
  short* albuf = (short*)(ws + 0x310000);
  float* pmax = (float*)(ws + 0x350000);
  unsigned* flags = (unsigned*)(ws + 0x358000);
  float* out = (float*)d_out;

  hipMemsetAsync(flags, 0, 64 * sizeof(unsigned), stream);
  k_rowstat<<<1024, 256, 0, stream>>>(trans, rstat);
  k_fillP<<<64, 256, 0, stream>>>(trans, rstat, P_frag);
  k_emis<<<1024, 256, 0, stream>>>(emis, emisP);
  k_prior<<<1, 256, 0, stream>>>(prior, prior_p);
  hmm_main<<<64, 256, 0, stream>>>(value, prior_p, P_frag, emisP, albuf, pmax, flags, out);
}

// Round 2
// 1013.618 us; speedup vs baseline: 3.4708x; 3.4708x over previous
//
#include <hip/hip_runtime.h>
#include <hip/hip_bf16.h>

// HMM forward, linear-space with FIXED x512 per-step scaling (folded into E).
// S=1024 states, V=512 obs, B=64 batch, T=128 steps.
// 64 persistent wgs x 256 thr; wg w owns output j-tile [16w,16w+16) for all batches.
// Cross-wg data via cache-bypassing (sc0 sc1) loads/stores; sync via per-step
// arrive counters. NO threadfence / cache invalidates in the hot loop.
//
// ws layout (bytes):
//   P_frag : 0x000000  [64 wg][32 kk][64 lane][8] bf16  (2 MB)   B-frags of softmax(trans)
//   emisP  : 0x200000  [1024][512] bf16 (x512)          (1 MB)
//   prior_p: 0x300000  [1024] f32
//   rstat  : 0x301000  [1024][2] f32
//   albuf  : 0x310000  [2][64][1024] bf16 ping-pong alpha (256 KB)
//   cnt    : 0x350000  [128] u32 arrive counters

typedef __attribute__((ext_vector_type(8))) short short8;
typedef __attribute__((ext_vector_type(4))) float f32x4;

__device__ __forceinline__ float bf2f(short x) {
  unsigned u = ((unsigned)(unsigned short)x) << 16;
  return __builtin_bit_cast(float, u);
}
__device__ __forceinline__ short f2bf(float f) {
  unsigned u = __builtin_bit_cast(unsigned, f);
  u += 0x7fffu + ((u >> 16) & 1u);
  return (short)(u >> 16);
}
__device__ __forceinline__ float waveReduceMax(float v) {
  #pragma unroll
  for (int d = 1; d < 64; d <<= 1) v = fmaxf(v, __shfl_xor(v, d, 64));
  return v;
}
__device__ __forceinline__ float waveReduceSum(float v) {
  #pragma unroll
  for (int d = 1; d < 64; d <<= 1) v += __shfl_xor(v, d, 64);
  return v;
}

// coherent (L2-bypassing) scalar bf16 store
__device__ __forceinline__ void store_bf16_coh(short* p, short v) {
  asm volatile("global_store_short %0, %1, off sc0 sc1" :: "v"(p), "v"(v) : "memory");
}
// coherent scalar bf16 load (blocking; epilogue only)
__device__ __forceinline__ float load_bf16_coh(const short* p) {
  unsigned short r;
  asm volatile("global_load_ushort %0, %1, off sc0 sc1\n\ts_waitcnt vmcnt(0)"
               : "=v"(r) : "v"(p) : "memory");
  return bf2f((short)r);
}

// ---------------- precompute kernels ----------------

__global__ __launch_bounds__(256) void k_rowstat(const float* __restrict__ x,
                                                 float* __restrict__ rstat) {
  __shared__ float sm[8];
  const int row = blockIdx.x;
  const float* p = x + row * 1024;
  const int tid = threadIdx.x;
  float m = -1e30f;
  for (int i = tid; i < 1024; i += 256) m = fmaxf(m, p[i]);
  m = waveReduceMax(m);
  if ((tid & 63) == 0) sm[tid >> 6] = m;
  __syncthreads();
  m = fmaxf(fmaxf(sm[0], sm[1]), fmaxf(sm[2], sm[3]));
  float s = 0.f;
  for (int i = tid; i < 1024; i += 256) s += __expf(p[i] - m);
  s = waveReduceSum(s);
  if ((tid & 63) == 0) sm[4 + (tid >> 6)] = s;
  __syncthreads();
  if (tid == 0) {
    float tot = sm[4] + sm[5] + sm[6] + sm[7];
    rstat[row * 2] = m;
    rstat[row * 2 + 1] = 1.0f / tot;
  }
}

// B-frag layout for v_mfma_f32_16x16x32_bf16: lane l holds col n=l&15, k=(l>>4)*8+e
__global__ __launch_bounds__(256) void k_fillP(const float* __restrict__ trans,
                                               const float* __restrict__ rstat,
                                               short* __restrict__ P_frag) {
  __shared__ float st[512];  // [32 i_local][16 j_local]
  const int w = blockIdx.x, tid = threadIdx.x;
  for (int kk = 0; kk < 32; ++kk) {
    for (int idx = tid; idx < 512; idx += 256) {
      int il = idx >> 4, jl = idx & 15;
      int i = kk * 32 + il, j = w * 16 + jl;
      float m = rstat[i * 2], invs = rstat[i * 2 + 1];
      st[idx] = __expf(trans[i * 1024 + j] - m) * invs;
    }
    __syncthreads();
    for (int idx = tid; idx < 512; idx += 256) {
      int lane = idx >> 3, e = idx & 7;
      int il = ((lane >> 4) & 3) * 8 + e, jl = lane & 15;
      P_frag[w * 16384 + kk * 512 + idx] = f2bf(st[il * 16 + jl]);
    }
    __syncthreads();
  }
}

// emission probabilities x512: row softmax over 512, bf16
__global__ __launch_bounds__(256) void k_emis(const float* __restrict__ x,
                                              short* __restrict__ o) {
  __shared__ float sm[8];
  const int row = blockIdx.x;
  const float* p = x + row * 512;
  const int tid = threadIdx.x;
  float m = -1e30f;
  for (int i = tid; i < 512; i += 256) m = fmaxf(m, p[i]);
  m = waveReduceMax(m);
  if ((tid & 63) == 0) sm[tid >> 6] = m;
  __syncthreads();
  m = fmaxf(fmaxf(sm[0], sm[1]), fmaxf(sm[2], sm[3]));
  float s = 0.f;
  for (int i = tid; i < 512; i += 256) s += __expf(p[i] - m);
  s = waveReduceSum(s);
  if ((tid & 63) == 0) sm[4 + (tid >> 6)] = s;
  __syncthreads();
  float invs = 512.0f / (sm[4] + sm[5] + sm[6] + sm[7]);
  for (int i = tid; i < 512; i += 256) o[row * 512 + i] = f2bf(__expf(p[i] - m) * invs);
}

__global__ __launch_bounds__(256) void k_prior(const float* __restrict__ x,
                                               float* __restrict__ o) {
  __shared__ float sm[8];
  const int tid = threadIdx.x;
  float m = -1e30f;
  for (int i = tid; i < 1024; i += 256) m = fmaxf(m, x[i]);
  m = waveReduceMax(m);
  if ((tid & 63) == 0) sm[tid >> 6] = m;
  __syncthreads();
  m = fmaxf(fmaxf(sm[0], sm[1]), fmaxf(sm[2], sm[3]));
  float s = 0.f;
  for (int i = tid; i < 1024; i += 256) s += __expf(x[i] - m);
  s = waveReduceSum(s);
  if ((tid & 63) == 0) sm[4 + (tid >> 6)] = s;
  __syncthreads();
  float invs = 1.0f / (sm[4] + sm[5] + sm[6] + sm[7]);
  for (int i = tid; i < 1024; i += 256) o[i] = __expf(x[i] - m) * invs;
}

// ---------------- main persistent kernel ----------------

// batched coherent A-frag loads: base ptr in ab, byte offset immediate
#define LA(OFF) asm volatile("global_load_dwordx4 %0, %1, off offset:" #OFF " sc0 sc1" \
                             : "=v"(a[OFF / 64]) : "v"(ab) : "memory")

__global__ __launch_bounds__(256, 1) void hmm_main(
    const int* __restrict__ value, const float* __restrict__ prior_p,
    const short* __restrict__ P_frag, const short* __restrict__ emisP,
    short* __restrict__ albuf, unsigned int* __restrict__ cnt,
    float* __restrict__ out) {
  __shared__ __align__(16) short p_lds[16384];    // [32 kk][64 lane][8] B-frags
  __shared__ __align__(16) short e_lds[16 * 513]; // emis rows (x512), padded
  __shared__ int v_lds[128 * 64];                 // value transposed [t][b]
  __shared__ float red_lds[4];

  const int w = blockIdx.x;
  const int tid = threadIdx.x;
  const int lane = tid & 63;
  const int wid = tid >> 6;          // wave id = M-tile (16 batches each)
  const int jl = lane & 15;
  const int kg = lane >> 4;
  const int b0 = wid * 16 + kg * 4;  // C rows b0..b0+3

  {
    const short8* src = (const short8*)(P_frag + w * 16384);
    short8* dst = (short8*)p_lds;
    #pragma unroll
    for (int i = 0; i < 8; ++i) dst[tid + i * 256] = src[tid + i * 256];
  }
  for (int i = tid; i < 16 * 512; i += 256) {
    int r = i >> 9, c = i & 511;
    e_lds[r * 513 + c] = emisP[(w * 16 + r) * 512 + c];
  }
  for (int i = tid; i < 8192; i += 256)
    v_lds[(i & 127) * 64 + (i >> 7)] = value[i];  // value[b][t] -> v_lds[t][b]
  __syncthreads();

  // ---- t = 0: alpha0 = prior * (512*E0) ----
  {
    float pj = prior_p[w * 16 + jl];
    #pragma unroll
    for (int r = 0; r < 4; ++r) {
      int obs = v_lds[b0 + r];
      float sv = pj * bf2f(e_lds[jl * 513 + obs]);
      store_bf16_coh(albuf + (b0 + r) * 1024 + w * 16 + jl, f2bf(sv));
    }
    asm volatile("s_waitcnt vmcnt(0)" ::: "memory");
    __syncthreads();
    if (tid == 0)
      __hip_atomic_fetch_add(&cnt[0], 1u, __ATOMIC_RELEASE, __HIP_MEMORY_SCOPE_AGENT);
  }

  const short* abase0 = albuf + (wid * 16 + jl) * 1024 + kg * 8;  // A row=batch, 8 contig k
  const short8* bb = (const short8*)p_lds + lane;

  // ---- main recurrence ----
  for (int t = 1; t < 128; ++t) {
    if (tid == 0) {
      int tries = 0;
      while (__hip_atomic_load(&cnt[t - 1], __ATOMIC_RELAXED, __HIP_MEMORY_SCOPE_AGENT) < 64u) {
        if (++tries > (1 << 22)) break;  // safety: no infinite hang
        __builtin_amdgcn_s_sleep(1);
      }
    }
    __syncthreads();

    const void* ab = (const void*)(abase0 + ((t - 1) & 1) * 65536);
    short8 a[32];
    LA(0);    LA(64);   LA(128);  LA(192);  LA(256);  LA(320);  LA(384);  LA(448);
    LA(512);  LA(576);  LA(640);  LA(704);  LA(768);  LA(832);  LA(896);  LA(960);
    LA(1024); LA(1088); LA(1152); LA(1216); LA(1280); LA(1344); LA(1408); LA(1472);
    LA(1536); LA(1600); LA(1664); LA(1728); LA(1792); LA(1856); LA(1920); LA(1984);
    asm volatile("s_waitcnt vmcnt(0)" ::: "memory");
    __builtin_amdgcn_sched_barrier(0);

    f32x4 acc0 = {0.f, 0.f, 0.f, 0.f}, acc1 = {0.f, 0.f, 0.f, 0.f};
    #pragma unroll
    for (int kk = 0; kk < 32; kk += 2) {
      acc0 = __builtin_amdgcn_mfma_f32_16x16x32_bf16(a[kk], bb[kk * 64], acc0, 0, 0, 0);
      acc1 = __builtin_amdgcn_mfma_f32_16x16x32_bf16(a[kk + 1], bb[(kk + 1) * 64], acc1, 0, 0, 0);
    }

    short* acur = albuf + (t & 1) * 65536;
    #pragma unroll
    for (int r = 0; r < 4; ++r) {
      int obs = v_lds[t * 64 + b0 + r];
      float E = bf2f(e_lds[jl * 513 + obs]);
      float sv = (acc0[r] + acc1[r]) * E;
      store_bf16_coh(acur + (b0 + r) * 1024 + w * 16 + jl, f2bf(sv));
    }
    asm volatile("s_waitcnt vmcnt(0)" ::: "memory");
    __syncthreads();
    if (tid == 0)
      __hip_atomic_fetch_add(&cnt[t], 1u, __ATOMIC_RELEASE, __HIP_MEMORY_SCOPE_AGENT);
  }

  // ---- final: out[w] = log(sum_j alpha_127[w][j]) - 128*ln(512) ----
  if (tid == 0) {
    int tries = 0;
    while (__hip_atomic_load(&cnt[127], __ATOMIC_RELAXED, __HIP_MEMORY_SCOPE_AGENT) < 64u) {
      if (++tries > (1 << 22)) break;
      __builtin_amdgcn_s_sleep(1);
    }
  }
  __syncthreads();
  const short* arow = albuf + 65536 + w * 1024;  // t=127 -> half 1
  float part = 0.f;
  #pragma unroll
  for (int q = 0; q < 4; ++q) part += load_bf16_coh(arow + tid + q * 256);
  part = waveReduceSum(part);
  if (lane == 0) red_lds[wid] = part;
  __syncthreads();
  if (tid == 0) {
    float ssum = red_lds[0] + red_lds[1] + red_lds[2] + red_lds[3];
    out[w] = logf(ssum) - 798.5055520050569f;  // 128 * ln(512)
  }
}

extern "C" void kernel_launch(void* const* d_in, const int* in_sizes, int n_in,
                              void* d_out, int out_size, void* d_ws, size_t ws_size,
                              hipStream_t stream) {
  const int* value = (const int*)d_in[0];
  const float* prior = (const float*)d_in[1];
  const float* trans = (const float*)d_in[2];
  const float* emis = (const float*)d_in[3];
  char* ws = (char*)d_ws;
  short* P_frag = (short*)(ws + 0x000000);
  short* emisP = (short*)(ws + 0x200000);
  float* prior_p = (float*)(ws + 0x300000);
  float* rstat = (float*)(ws + 0x301000);
  short* albuf = (short*)(ws + 0x310000);
  unsigned* cnt = (unsigned*)(ws + 0x350000);
  float* out = (float*)d_out;

  hipMemsetAsync(cnt, 0, 128 * sizeof(unsigned), stream);
  k_rowstat<<<1024, 256, 0, stream>>>(trans, rstat);
  k_fillP<<<64, 256, 0, stream>>>(trans, rstat, P_frag);
  k_emis<<<1024, 256, 0, stream>>>(emis, emisP);
  k_prior<<<1, 256, 0, stream>>>(prior, prior_p);
  hmm_main<<<64, 256, 0, stream>>>(value, prior_p, P_frag, emisP, albuf, cnt, out);
}

// Round 3
// 828.672 us; speedup vs baseline: 4.2454x; 1.2232x over previous
//
#include <hip/hip_runtime.h>
#include <hip/hip_bf16.h>

// HMM forward, linear space, fixed x512 scaling folded into E.
// S=1024, V=512, B=64, T=128.
// 4 independent sync domains x 16 batches. Domain d served by 16 wgs
// (member m owns output cols [64m, 64m+64)). Per-step sync: each wg stores
// ONE flag word (value t+1, unique slot) after vmcnt(0); wave 0 of each wg
// exact-match polls its domain's 16 flags. All cross-wg data via sc0 sc1
// (coherence-point) loads/stores; no fences, no atomics, no L2 invalidates.
//
// ws layout (bytes):
//   P_frag : 0x000000  [64 tile][32 kk][64 lane][8] bf16 (2 MB)  B-frags of softmax(trans)
//   emisT  : 0x200000  [512 obs][1024 j] bf16 (x512)     (1 MB)
//   prior_p: 0x300000  [1024] f32
//   rstat  : 0x301000  [1024][2] f32
//   albuf  : 0x310000  [2][64][1024] bf16 ping-pong alpha (256 KB)
//   flg    : 0x350000  [4 dom][128 t][16 m] u32          (32 KB)

typedef __attribute__((ext_vector_type(8))) short short8;
typedef __attribute__((ext_vector_type(4))) float f32x4;

__device__ __forceinline__ float bf2f(short x) {
  unsigned u = ((unsigned)(unsigned short)x) << 16;
  return __builtin_bit_cast(float, u);
}
__device__ __forceinline__ short f2bf(float f) {
  unsigned u = __builtin_bit_cast(unsigned, f);
  u += 0x7fffu + ((u >> 16) & 1u);
  return (short)(u >> 16);
}
__device__ __forceinline__ float waveReduceMax(float v) {
  #pragma unroll
  for (int d = 1; d < 64; d <<= 1) v = fmaxf(v, __shfl_xor(v, d, 64));
  return v;
}
__device__ __forceinline__ float waveReduceSum(float v) {
  #pragma unroll
  for (int d = 1; d < 64; d <<= 1) v += __shfl_xor(v, d, 64);
  return v;
}

__device__ __forceinline__ void store_bf16_coh(short* p, short v) {
  asm volatile("global_store_short %0, %1, off sc0 sc1" :: "v"(p), "v"(v) : "memory");
}
__device__ __forceinline__ void store_u32_coh(unsigned* p, unsigned v) {
  asm volatile("global_store_dword %0, %1, off sc0 sc1" :: "v"(p), "v"(v) : "memory");
}
__device__ __forceinline__ unsigned load_u32_coh(const unsigned* p) {
  unsigned r;
  asm volatile("global_load_dword %0, %1, off sc0 sc1\n\ts_waitcnt vmcnt(0)"
               : "=v"(r) : "v"(p) : "memory");
  return r;
}
__device__ __forceinline__ short8 load_short8_coh(const short* p) {
  short8 r;
  asm volatile("global_load_dwordx4 %0, %1, off sc0 sc1\n\ts_waitcnt vmcnt(0)"
               : "=v"(r) : "v"(p) : "memory");
  return r;
}

// ---------------- precompute kernels ----------------

__global__ __launch_bounds__(256) void k_rowstat(const float* __restrict__ x,
                                                 float* __restrict__ rstat) {
  __shared__ float sm[8];
  const int row = blockIdx.x;
  const float* p = x + row * 1024;
  const int tid = threadIdx.x;
  float m = -1e30f;
  for (int i = tid; i < 1024; i += 256) m = fmaxf(m, p[i]);
  m = waveReduceMax(m);
  if ((tid & 63) == 0) sm[tid >> 6] = m;
  __syncthreads();
  m = fmaxf(fmaxf(sm[0], sm[1]), fmaxf(sm[2], sm[3]));
  float s = 0.f;
  for (int i = tid; i < 1024; i += 256) s += __expf(p[i] - m);
  s = waveReduceSum(s);
  if ((tid & 63) == 0) sm[4 + (tid >> 6)] = s;
  __syncthreads();
  if (tid == 0) {
    float tot = sm[4] + sm[5] + sm[6] + sm[7];
    rstat[row * 2] = m;
    rstat[row * 2 + 1] = 1.0f / tot;
  }
}

// B-frag scatter: tile w (16 cols) -> P_frag[w][kk][lane][8]
__global__ __launch_bounds__(256) void k_fillP(const float* __restrict__ trans,
                                               const float* __restrict__ rstat,
                                               short* __restrict__ P_frag) {
  __shared__ float st[512];  // [32 i_local][16 j_local]
  const int w = blockIdx.x, tid = threadIdx.x;
  for (int kk = 0; kk < 32; ++kk) {
    for (int idx = tid; idx < 512; idx += 256) {
      int il = idx >> 4, jl = idx & 15;
      int i = kk * 32 + il, j = w * 16 + jl;
      float m = rstat[i * 2], invs = rstat[i * 2 + 1];
      st[idx] = __expf(trans[i * 1024 + j] - m) * invs;
    }
    __syncthreads();
    for (int idx = tid; idx < 512; idx += 256) {
      int lane = idx >> 3, e = idx & 7;
      int il = ((lane >> 4) & 3) * 8 + e, jl = lane & 15;
      P_frag[w * 16384 + kk * 512 + idx] = f2bf(st[il * 16 + jl]);
    }
    __syncthreads();
  }
}

// emission: row-j softmax over 512 obs, x512, stored TRANSPOSED: emisT[v][j]
__global__ __launch_bounds__(256) void k_emis(const float* __restrict__ x,
                                              short* __restrict__ o) {
  __shared__ float sm[8];
  const int row = blockIdx.x;  // state j
  const float* p = x + row * 512;
  const int tid = threadIdx.x;
  float m = -1e30f;
  for (int i = tid; i < 512; i += 256) m = fmaxf(m, p[i]);
  m = waveReduceMax(m);
  if ((tid & 63) == 0) sm[tid >> 6] = m;
  __syncthreads();
  m = fmaxf(fmaxf(sm[0], sm[1]), fmaxf(sm[2], sm[3]));
  float s = 0.f;
  for (int i = tid; i < 512; i += 256) s += __expf(p[i] - m);
  s = waveReduceSum(s);
  if ((tid & 63) == 0) sm[4 + (tid >> 6)] = s;
  __syncthreads();
  float invs = 512.0f / (sm[4] + sm[5] + sm[6] + sm[7]);
  for (int i = tid; i < 512; i += 256)
    o[i * 1024 + row] = f2bf(__expf(p[i] - m) * invs);
}

__global__ __launch_bounds__(256) void k_prior(const float* __restrict__ x,
                                               float* __restrict__ o) {
  __shared__ float sm[8];
  const int tid = threadIdx.x;
  float m = -1e30f;
  for (int i = tid; i < 1024; i += 256) m = fmaxf(m, x[i]);
  m = waveReduceMax(m);
  if ((tid & 63) == 0) sm[tid >> 6] = m;
  __syncthreads();
  m = fmaxf(fmaxf(sm[0], sm[1]), fmaxf(sm[2], sm[3]));
  float s = 0.f;
  for (int i = tid; i < 1024; i += 256) s += __expf(x[i] - m);
  s = waveReduceSum(s);
  if ((tid & 63) == 0) sm[4 + (tid >> 6)] = s;
  __syncthreads();
  float invs = 1.0f / (sm[4] + sm[5] + sm[6] + sm[7]);
  for (int i = tid; i < 1024; i += 256) o[i] = __expf(x[i] - m) * invs;
}

// ---------------- main persistent kernel ----------------

#define LA(OFF) asm volatile("global_load_dwordx4 %0, %1, off offset:" #OFF " sc0 sc1" \
                             : "=v"(a[OFF / 64]) : "v"(ab) : "memory")

__global__ __launch_bounds__(256, 1) void hmm_main(
    const int* __restrict__ value, const float* __restrict__ prior_p,
    const short* __restrict__ P_frag, const short* __restrict__ emisT,
    short* __restrict__ albuf, unsigned int* __restrict__ flg,
    float* __restrict__ out) {
  __shared__ __align__(16) short p_lds[65536];  // [4 wv][32 kk][64 lane][8] = 128 KB
  __shared__ int v_lds[128 * 16];               // obs for own domain: [t][b_loc]

  const int bx = blockIdx.x;
  const int d = bx & 3;        // domain (batches 16d..16d+16)
  const int m = bx >> 2;       // member (cols 64m..64m+64)
  const int tid = threadIdx.x;
  const int lane = tid & 63;
  const int wid = tid >> 6;    // wave -> 16-col subtile
  const int jl = lane & 15;
  const int kg = lane >> 4;
  const int jcol = (m * 4 + wid) * 16 + jl;   // this thread's output column
  const int bloc0 = kg * 4;                   // C rows b_loc = kg*4 + r

  // prologue: P slice (128 KB contiguous) -> LDS; own obs -> LDS
  {
    const short8* src = (const short8*)P_frag + m * 8192;
    short8* dst = (short8*)p_lds;
    #pragma unroll
    for (int i = 0; i < 32; ++i) dst[tid + i * 256] = src[tid + i * 256];
  }
  for (int i = tid; i < 2048; i += 256) {
    int bl = i >> 7, tt = i & 127;
    v_lds[tt * 16 + bl] = value[(d * 16 + bl) * 128 + tt];
  }
  __syncthreads();

  // ---- t = 0: alpha0 = prior * (512*E0) ----
  {
    float pj = prior_p[jcol];
    #pragma unroll
    for (int r = 0; r < 4; ++r) {
      int obs = v_lds[bloc0 + r];
      float E = bf2f(emisT[obs * 1024 + jcol]);
      store_bf16_coh(albuf + (d * 16 + bloc0 + r) * 1024 + jcol, f2bf(pj * E));
    }
    asm volatile("s_waitcnt vmcnt(0)" ::: "memory");
    __syncthreads();
    if (tid == 0) store_u32_coh(&flg[d * 2048 + 0 * 16 + m], 1u);
  }

  const short* abase0 = albuf + (d * 16 + jl) * 1024 + kg * 8;  // A row = batch
  const short8* bb = (const short8*)p_lds + wid * 2048 + lane;

  // ---- main recurrence ----
  for (int t = 1; t < 128; ++t) {
    // E prefetch for this step (normal cached loads; L2-hot, off critical path)
    float Ev[4];
    #pragma unroll
    for (int r = 0; r < 4; ++r) {
      int obs = v_lds[t * 16 + bloc0 + r];
      Ev[r] = bf2f(emisT[obs * 1024 + jcol]);
    }

    if (wid == 0) {
      const unsigned* fp = flg + d * 2048 + (t - 1) * 16 + (lane & 15);
      int tries = 0;
      while (true) {
        unsigned f = load_u32_coh(fp);
        if (__all((int)(f == (unsigned)t))) break;
        if (++tries > (1 << 17)) break;  // safety: no infinite hang
      }
    }
    __syncthreads();

    const void* ab = (const void*)(abase0 + ((t - 1) & 1) * 65536);
    short8 a[32];
    LA(0);    LA(64);   LA(128);  LA(192);  LA(256);  LA(320);  LA(384);  LA(448);
    LA(512);  LA(576);  LA(640);  LA(704);  LA(768);  LA(832);  LA(896);  LA(960);
    LA(1024); LA(1088); LA(1152); LA(1216); LA(1280); LA(1344); LA(1408); LA(1472);
    LA(1536); LA(1600); LA(1664); LA(1728); LA(1792); LA(1856); LA(1920); LA(1984);
    asm volatile("s_waitcnt vmcnt(0)" ::: "memory");
    __builtin_amdgcn_sched_barrier(0);

    f32x4 acc0 = {0.f, 0.f, 0.f, 0.f}, acc1 = {0.f, 0.f, 0.f, 0.f};
    #pragma unroll
    for (int kk = 0; kk < 32; kk += 2) {
      acc0 = __builtin_amdgcn_mfma_f32_16x16x32_bf16(a[kk], bb[kk * 64], acc0, 0, 0, 0);
      acc1 = __builtin_amdgcn_mfma_f32_16x16x32_bf16(a[kk + 1], bb[(kk + 1) * 64], acc1, 0, 0, 0);
    }

    short* acur = albuf + (t & 1) * 65536;
    #pragma unroll
    for (int r = 0; r < 4; ++r) {
      float sv = (acc0[r] + acc1[r]) * Ev[r];
      store_bf16_coh(acur + (d * 16 + bloc0 + r) * 1024 + jcol, f2bf(sv));
    }
    asm volatile("s_waitcnt vmcnt(0)" ::: "memory");
    __syncthreads();
    if (tid == 0) store_u32_coh(&flg[d * 2048 + t * 16 + m], (unsigned)(t + 1));
  }

  // ---- epilogue: member 0 of each domain reduces its 16 batches ----
  if (m != 0) return;
  if (wid == 0) {
    const unsigned* fp = flg + d * 2048 + 127 * 16 + (lane & 15);
    int tries = 0;
    while (true) {
      unsigned f = load_u32_coh(fp);
      if (__all((int)(f == 128u))) break;
      if (++tries > (1 << 17)) break;
    }
  }
  __syncthreads();
  {
    int row = tid >> 4, chunk = tid & 15;               // row 0..15, chunk 0..15
    const short* base = albuf + 65536 + (d * 16 + row) * 1024 + chunk * 64;
    float s = 0.f;
    #pragma unroll
    for (int q = 0; q < 8; ++q) {
      short8 v = load_short8_coh(base + q * 8);
      #pragma unroll
      for (int e = 0; e < 8; ++e) s += bf2f(v[e]);
    }
    #pragma unroll
    for (int msk = 1; msk < 16; msk <<= 1) s += __shfl_xor(s, msk, 64);
    if (chunk == 0) out[d * 16 + row] = logf(s) - 798.5055520050569f;  // 128*ln(512)
  }
}

extern "C" void kernel_launch(void* const* d_in, const int* in_sizes, int n_in,
                              void* d_out, int out_size, void* d_ws, size_t ws_size,
                              hipStream_t stream) {
  const int* value = (const int*)d_in[0];
  const float* prior = (const float*)d_in[1];
  const float* trans = (const float*)d_in[2];
  const float* emis = (const float*)d_in[3];
  char* ws = (char*)d_ws;
  short* P_frag = (short*)(ws + 0x000000);
  short* emisT = (short*)(ws + 0x200000);
  float* prior_p = (float*)(ws + 0x300000);
  float* rstat = (float*)(ws + 0x301000);
  short* albuf = (short*)(ws + 0x310000);
  unsigned* flg = (unsigned*)(ws + 0x350000);
  float* out = (float*)d_out;

  k_rowstat<<<1024, 256, 0, stream>>>(trans, rstat);
  k_fillP<<<64, 256, 0, stream>>>(trans, rstat, P_frag);
  k_emis<<<1024, 256, 0, stream>>>(emis, emisT);
  k_prior<<<1, 256, 0, stream>>>(prior, prior_p);
  hmm_main<<<64, 256, 0, stream>>>(value, prior_p, P_frag, emisT, albuf, flg, out);
}

// Round 4
// 747.097 us; speedup vs baseline: 4.7089x; 1.1092x over previous
//
#include <hip/hip_runtime.h>
#include <hip/hip_bf16.h>

// HMM forward, linear space, fixed x512 scaling folded into E.
// S=1024, V=512, B=64, T=128.
// 4 independent sync domains x 16 batches; 16 wgs per domain (member m owns
// cols [64m, 64m+64)). Alpha lives in a 128-deep FIFO (one slot per step) so
// consumers can use CACHED loads (every address written once per launch);
// producers store through to the coherence point (sc0 sc1). Per-step sync:
// one flag word per (domain, t, member), exact-match polled.
//
// ws layout (bytes):
//   P_frag : 0x000000  [64 tile][32 kk][64 lane][8] bf16 (2 MB)
//   emisT  : 0x200000  [512 obs][1024 j] bf16 (x512)     (1 MB)
//   prior_p: 0x300000  [1024] f32
//   rstat  : 0x301000  [1024][2] f32
//   flg    : 0x303000  [4 dom][128 t][16 m] u32          (32 KB)
//   albuf  : 0x310000  [DEPTH][64][1024] bf16 FIFO       (16 MB deep / 256 KB shallow)

typedef __attribute__((ext_vector_type(8))) short short8;
typedef __attribute__((ext_vector_type(4))) float f32x4;

#define ALBUF_OFF 0x310000
#define DEEP_WS_NEED (ALBUF_OFF + 128 * 131072)

__device__ __forceinline__ float bf2f(short x) {
  unsigned u = ((unsigned)(unsigned short)x) << 16;
  return __builtin_bit_cast(float, u);
}
__device__ __forceinline__ short f2bf(float f) {
  unsigned u = __builtin_bit_cast(unsigned, f);
  u += 0x7fffu + ((u >> 16) & 1u);
  return (short)(u >> 16);
}
__device__ __forceinline__ float waveReduceMax(float v) {
  #pragma unroll
  for (int d = 1; d < 64; d <<= 1) v = fmaxf(v, __shfl_xor(v, d, 64));
  return v;
}
__device__ __forceinline__ float waveReduceSum(float v) {
  #pragma unroll
  for (int d = 1; d < 64; d <<= 1) v += __shfl_xor(v, d, 64);
  return v;
}

__device__ __forceinline__ void store_u32_coh(unsigned* p, unsigned v) {
  asm volatile("global_store_dword %0, %1, off sc0 sc1" :: "v"(p), "v"(v) : "memory");
}
__device__ __forceinline__ unsigned load_u32_coh(const unsigned* p) {
  unsigned r;
  asm volatile("global_load_dword %0, %1, off sc0 sc1\n\ts_waitcnt vmcnt(0)"
               : "=v"(r) : "v"(p) : "memory");
  return r;
}
__device__ __forceinline__ void store_short8_coh(short* p, short8 v) {
  asm volatile("global_store_dwordx4 %0, %1, off sc0 sc1" :: "v"(p), "v"(v) : "memory");
}

// ---------------- precompute kernels ----------------

__global__ __launch_bounds__(256) void k_rowstat(const float* __restrict__ x,
                                                 float* __restrict__ rstat) {
  __shared__ float sm[8];
  const int row = blockIdx.x;
  const float* p = x + row * 1024;
  const int tid = threadIdx.x;
  float m = -1e30f;
  for (int i = tid; i < 1024; i += 256) m = fmaxf(m, p[i]);
  m = waveReduceMax(m);
  if ((tid & 63) == 0) sm[tid >> 6] = m;
  __syncthreads();
  m = fmaxf(fmaxf(sm[0], sm[1]), fmaxf(sm[2], sm[3]));
  float s = 0.f;
  for (int i = tid; i < 1024; i += 256) s += __expf(p[i] - m);
  s = waveReduceSum(s);
  if ((tid & 63) == 0) sm[4 + (tid >> 6)] = s;
  __syncthreads();
  if (tid == 0) {
    float tot = sm[4] + sm[5] + sm[6] + sm[7];
    rstat[row * 2] = m;
    rstat[row * 2 + 1] = 1.0f / tot;
  }
}

// B-frag scatter: tile w (16 cols) -> P_frag[w][kk][lane][8]
__global__ __launch_bounds__(256) void k_fillP(const float* __restrict__ trans,
                                               const float* __restrict__ rstat,
                                               short* __restrict__ P_frag) {
  __shared__ float st[512];  // [32 i_local][16 j_local]
  const int w = blockIdx.x, tid = threadIdx.x;
  for (int kk = 0; kk < 32; ++kk) {
    for (int idx = tid; idx < 512; idx += 256) {
      int il = idx >> 4, jl = idx & 15;
      int i = kk * 32 + il, j = w * 16 + jl;
      float m = rstat[i * 2], invs = rstat[i * 2 + 1];
      st[idx] = __expf(trans[i * 1024 + j] - m) * invs;
    }
    __syncthreads();
    for (int idx = tid; idx < 512; idx += 256) {
      int lane = idx >> 3, e = idx & 7;
      int il = ((lane >> 4) & 3) * 8 + e, jl = lane & 15;
      P_frag[w * 16384 + kk * 512 + idx] = f2bf(st[il * 16 + jl]);
    }
    __syncthreads();
  }
}

// emission: row-j softmax over 512 obs, x512, stored TRANSPOSED: emisT[v][j]
__global__ __launch_bounds__(256) void k_emis(const float* __restrict__ x,
                                              short* __restrict__ o) {
  __shared__ float sm[8];
  const int row = blockIdx.x;  // state j
  const float* p = x + row * 512;
  const int tid = threadIdx.x;
  float m = -1e30f;
  for (int i = tid; i < 512; i += 256) m = fmaxf(m, p[i]);
  m = waveReduceMax(m);
  if ((tid & 63) == 0) sm[tid >> 6] = m;
  __syncthreads();
  m = fmaxf(fmaxf(sm[0], sm[1]), fmaxf(sm[2], sm[3]));
  float s = 0.f;
  for (int i = tid; i < 512; i += 256) s += __expf(p[i] - m);
  s = waveReduceSum(s);
  if ((tid & 63) == 0) sm[4 + (tid >> 6)] = s;
  __syncthreads();
  float invs = 512.0f / (sm[4] + sm[5] + sm[6] + sm[7]);
  for (int i = tid; i < 512; i += 256)
    o[i * 1024 + row] = f2bf(__expf(p[i] - m) * invs);
}

__global__ __launch_bounds__(256) void k_prior(const float* __restrict__ x,
                                               float* __restrict__ o) {
  __shared__ float sm[8];
  const int tid = threadIdx.x;
  float m = -1e30f;
  for (int i = tid; i < 1024; i += 256) m = fmaxf(m, x[i]);
  m = waveReduceMax(m);
  if ((tid & 63) == 0) sm[tid >> 6] = m;
  __syncthreads();
  m = fmaxf(fmaxf(sm[0], sm[1]), fmaxf(sm[2], sm[3]));
  float s = 0.f;
  for (int i = tid; i < 1024; i += 256) s += __expf(x[i] - m);
  s = waveReduceSum(s);
  if ((tid & 63) == 0) sm[4 + (tid >> 6)] = s;
  __syncthreads();
  float invs = 1.0f / (sm[4] + sm[5] + sm[6] + sm[7]);
  for (int i = tid; i < 1024; i += 256) o[i] = __expf(x[i] - m) * invs;
}

// ---------------- main persistent kernel ----------------

// uncached A-frag loads for the shallow (ping-pong) fallback path
#define LAU(OFF) asm volatile("global_load_dwordx4 %0, %1, off offset:" #OFF " sc0 sc1" \
                              : "=v"(a[OFF / 64]) : "v"(ab) : "memory")

template <bool DEEP>
__global__ __launch_bounds__(256, 1) void hmm_main(
    const int* __restrict__ value, const float* __restrict__ prior_p,
    const short* __restrict__ P_frag, const short* __restrict__ emisT,
    short* __restrict__ albuf, unsigned int* __restrict__ flg,
    float* __restrict__ out) {
  __shared__ __align__(16) short p_lds[65536];  // [4 wv][32 kk][64 lane][8] = 128 KB
  __shared__ int v_lds[128 * 16];               // obs for own domain: [t][b_loc]
  __shared__ __align__(16) short o_lds[16 * 80];// output bounce [16 b][80 pad]

  const int bx = blockIdx.x;
  const int d = bx & 3;        // domain (batches 16d..16d+16)
  const int m = bx >> 2;       // member (cols 64m..64m+64)
  const int tid = threadIdx.x;
  const int lane = tid & 63;
  const int wid = tid >> 6;    // wave -> 16-col subtile
  const int jl = lane & 15;
  const int kg = lane >> 4;
  const int jcol = m * 64 + wid * 16 + jl;    // this thread's output column
  const int bloc0 = kg * 4;                   // C rows b_loc = kg*4 + r

  // prologue: P slice (128 KB contiguous) -> LDS; own obs -> LDS
  {
    const short8* src = (const short8*)P_frag + m * 8192;
    short8* dst = (short8*)p_lds;
    #pragma unroll
    for (int i = 0; i < 32; ++i) dst[tid + i * 256] = src[tid + i * 256];
  }
  for (int i = tid; i < 2048; i += 256) {
    int bl = i >> 7, tt = i & 127;
    v_lds[tt * 16 + bl] = value[(d * 16 + bl) * 128 + tt];
  }
  __syncthreads();

  // ---- t = 0: alpha0 = prior * (512*E0) ----
  {
    float pj = prior_p[jcol];
    #pragma unroll
    for (int r = 0; r < 4; ++r) {
      int obs = v_lds[bloc0 + r];
      float sv = pj * bf2f(emisT[obs * 1024 + jcol]);
      o_lds[(bloc0 + r) * 80 + wid * 16 + jl] = f2bf(sv);
    }
    __syncthreads();
    if (tid < 128) {
      int row = tid >> 3, chunk = tid & 7;
      short8 v = *(const short8*)(o_lds + row * 80 + chunk * 8);
      store_short8_coh(albuf + (size_t)(d * 16 + row) * 1024 + m * 64 + chunk * 8, v);
    }
    asm volatile("s_waitcnt vmcnt(0)" ::: "memory");
    __syncthreads();
    if (tid == 0) store_u32_coh(&flg[d * 2048 + 0 * 16 + m], 1u);
  }

  const short8* bb = (const short8*)p_lds + wid * 2048 + lane;

  // E prefetch for t=1
  float Ev[4];
  #pragma unroll
  for (int r = 0; r < 4; ++r)
    Ev[r] = bf2f(emisT[v_lds[1 * 16 + bloc0 + r] * 1024 + jcol]);

  // ---- main recurrence ----
  for (int t = 1; t < 128; ++t) {
    if (wid == 0) {
      const unsigned* fp = flg + d * 2048 + (t - 1) * 16 + (lane & 15);
      int tries = 0;
      while (true) {
        unsigned f = load_u32_coh(fp);
        if (__all((int)(f == (unsigned)t))) break;
        if (++tries > (1 << 17)) break;  // safety: no infinite hang
      }
    }
    __syncthreads();

    short8 a[32];
    f32x4 acc0 = {0.f, 0.f, 0.f, 0.f}, acc1 = {0.f, 0.f, 0.f, 0.f};
    if (DEEP) {
      // cached loads from write-once FIFO slot t-1 (L1 absorbs 4-wave reuse)
      const short8* ab8 = (const short8*)(albuf + (size_t)(t - 1) * 65536 +
                                          (d * 16 + jl) * 1024 + kg * 8);
      #pragma unroll
      for (int kk = 0; kk < 32; ++kk) a[kk] = ab8[kk * 4];
    } else {
      const void* ab = (const void*)(albuf + (size_t)((t - 1) & 1) * 65536 +
                                     (d * 16 + jl) * 1024 + kg * 8);
      LAU(0);    LAU(64);   LAU(128);  LAU(192);  LAU(256);  LAU(320);  LAU(384);  LAU(448);
      LAU(512);  LAU(576);  LAU(640);  LAU(704);  LAU(768);  LAU(832);  LAU(896);  LAU(960);
      LAU(1024); LAU(1088); LAU(1152); LAU(1216); LAU(1280); LAU(1344); LAU(1408); LAU(1472);
      LAU(1536); LAU(1600); LAU(1664); LAU(1728); LAU(1792); LAU(1856); LAU(1920); LAU(1984);
      asm volatile("s_waitcnt vmcnt(0)" ::: "memory");
      __builtin_amdgcn_sched_barrier(0);
    }

    #pragma unroll
    for (int kk = 0; kk < 32; kk += 2) {
      acc0 = __builtin_amdgcn_mfma_f32_16x16x32_bf16(a[kk], bb[kk * 64], acc0, 0, 0, 0);
      acc1 = __builtin_amdgcn_mfma_f32_16x16x32_bf16(a[kk + 1], bb[(kk + 1) * 64], acc1, 0, 0, 0);
    }

    #pragma unroll
    for (int r = 0; r < 4; ++r) {
      float sv = (acc0[r] + acc1[r]) * Ev[r];
      o_lds[(bloc0 + r) * 80 + wid * 16 + jl] = f2bf(sv);
    }
    __syncthreads();
    {
      size_t slot = DEEP ? (size_t)t : (size_t)(t & 1);
      if (tid < 128) {
        int row = tid >> 3, chunk = tid & 7;
        short8 v = *(const short8*)(o_lds + row * 80 + chunk * 8);
        store_short8_coh(albuf + slot * 65536 + (size_t)(d * 16 + row) * 1024 +
                         m * 64 + chunk * 8, v);
      }
      asm volatile("s_waitcnt vmcnt(0)" ::: "memory");
    }
    __syncthreads();
    if (tid == 0) store_u32_coh(&flg[d * 2048 + t * 16 + m], (unsigned)(t + 1));

    // E prefetch for next step (overlaps with next poll)
    if (t < 127) {
      #pragma unroll
      for (int r = 0; r < 4; ++r)
        Ev[r] = bf2f(emisT[v_lds[(t + 1) * 16 + bloc0 + r] * 1024 + jcol]);
    }
  }

  // ---- epilogue: member 0 of each domain reduces its 16 batches ----
  if (m != 0) return;
  if (wid == 0) {
    const unsigned* fp = flg + d * 2048 + 127 * 16 + (lane & 15);
    int tries = 0;
    while (true) {
      unsigned f = load_u32_coh(fp);
      if (__all((int)(f == 128u))) break;
      if (++tries > (1 << 17)) break;
    }
  }
  __syncthreads();
  {
    size_t slot = DEEP ? (size_t)127 : (size_t)1;
    int row = tid >> 4, seg = tid & 15;  // 16 rows x 16 segs of 128 B
    const short8* base = (const short8*)(albuf + slot * 65536 +
                                         (size_t)(d * 16 + row) * 1024 + seg * 64);
    float s = 0.f;
    #pragma unroll
    for (int q = 0; q < 8; ++q) {
      short8 v = base[q];
      #pragma unroll
      for (int e = 0; e < 8; ++e) s += bf2f(v[e]);
    }
    #pragma unroll
    for (int msk = 1; msk < 16; msk <<= 1) s += __shfl_xor(s, msk, 64);
    if ((lane & 15) == 0) out[d * 16 + row] = logf(s) - 798.5055520050569f;  // 128*ln512
  }
}

extern "C" void kernel_launch(void* const* d_in, const int* in_sizes, int n_in,
                              void* d_out, int out_size, void* d_ws, size_t ws_size,
                              hipStream_t stream) {
  const int* value = (const int*)d_in[0];
  const float* prior = (const float*)d_in[1];
  const float* trans = (const float*)d_in[2];
  const float* emis = (const float*)d_in[3];
  char* ws = (char*)d_ws;
  short* P_frag = (short*)(ws + 0x000000);
  short* emisT = (short*)(ws + 0x200000);
  float* prior_p = (float*)(ws + 0x300000);
  float* rstat = (float*)(ws + 0x301000);
  unsigned* flg = (unsigned*)(ws + 0x303000);
  short* albuf = (short*)(ws + ALBUF_OFF);
  float* out = (float*)d_out;

  k_rowstat<<<1024, 256, 0, stream>>>(trans, rstat);
  k_fillP<<<64, 256, 0, stream>>>(trans, rstat, P_frag);
  k_emis<<<1024, 256, 0, stream>>>(emis, emisT);
  k_prior<<<1, 256, 0, stream>>>(prior, prior_p);
  if (ws_size >= (size_t)DEEP_WS_NEED) {
    hmm_main<true><<<64, 256, 0, stream>>>(value, prior_p, P_frag, emisT, albuf, flg, out);
  } else {
    hmm_main<false><<<64, 256, 0, stream>>>(value, prior_p, P_frag, emisT, albuf, flg, out);
  }
}